// Round 1
// baseline (41387.729 us; speedup 1.0000x reference)
//
#include <hip/hip_runtime.h>
#include <math.h>

// Grid-LSTM: B=128, T=256, L=2, H=512, fp32.
// Per step: 4 dependent LSTM cells, each gates = [x|h](128x1024) @ Wcat(1024x2048) + b.
// Round 1: correct fp32 baseline. One kernel launch per cell (1024 launches, graph-captured).

static constexpr int Hn = 512;
static constexpr int Bn = 128;
static constexpr int Tn = 256;
static constexpr long THn = (long)Tn * Hn;   // 131072
static constexpr int Kc = 1024;              // 2H (x | h concat)
static constexpr int Nc = 2048;              // 4H gates

// ws layout (float offsets)
static constexpr long WCAT_OFF = 0;                         // 4 cells * 1024 * 2048 = 8388608
static constexpr long BSUM_OFF = WCAT_OFF + 4L * Kc * Nc;   // 4 * 2048
static constexpr long H0A_OFF  = BSUM_OFF + 4L * Nc;
static constexpr long H0B_OFF  = H0A_OFF + (long)Bn * Hn;
static constexpr long H1_OFF   = H0B_OFF + (long)Bn * Hn;   // [2 parity][2 layer][B][H]
static constexpr long M1_OFF   = H1_OFF + 4L * Bn * Hn;     // [2 layer][B][H]
static constexpr long M0_OFF   = M1_OFF + 2L * Bn * Hn;     // [B][H]

// ---- One-time weight transform: Wcat[cell][k][4j+g] ----
// k<512 -> Wih[l][s][g*512+j][k] ; k>=512 -> Whh[l][s][g*512+j][k-512]
__global__ __launch_bounds__(256) void transform_w(const float* __restrict__ Wih,
                                                   const float* __restrict__ Whh,
                                                   float* __restrict__ Wcat) {
    long idx = (long)blockIdx.x * 256 + threadIdx.x;   // < 4*1024*2048
    int n4 = (int)(idx & 2047);
    long ck = idx >> 11;           // cell*1024 + k
    int k = (int)(ck & 1023);
    int cell = (int)(ck >> 10);
    int j = n4 >> 2, g = n4 & 3;
    int n = g * 512 + j;
    const float* src = (k < 512) ? Wih : Whh;
    int kk = k & 511;
    Wcat[idx] = src[((long)cell * 2048 + n) * 512 + kk];
}

__global__ __launch_bounds__(256) void transform_b(const float* __restrict__ bih,
                                                   const float* __restrict__ bhh,
                                                   float* __restrict__ bsum) {
    int idx = blockIdx.x * 256 + threadIdx.x;   // < 4*2048
    int n4 = idx & 2047;
    int cell = idx >> 11;
    int j = n4 >> 2, g = n4 & 3;
    int n = g * 512 + j;
    bsum[idx] = bih[cell * 2048 + n] + bhh[cell * 2048 + n];
}

// ---- Fused LSTM cell: GEMM (M=128,N=2048,K=1024) + bias + activations ----
// Tile: BM=16 (batch), BN=64 (gate cols = 16 hidden units), BK=32. 256 threads.
// Thread owns 1 batch row x 4 interleaved gate cols (one hidden unit) -> fused epilogue.
// Grid: (2048/64=32, 128/16=8) = 256 blocks.
__global__ __launch_bounds__(256) void lstm_cell(
    const float* __restrict__ x, long xStride,
    const float* __restrict__ h, long hStride,
    const float* __restrict__ c,          // nullptr => zeros
    const float* __restrict__ W,          // this cell's 1024x2048 interleaved slice
    const float* __restrict__ bsum,       // 2048 interleaved
    float* __restrict__ hOut,             // [B][H] stride 512
    float* __restrict__ cOut,             // [B][H] stride 512
    float* __restrict__ hOut2,            // nullptr or stride THn (d_out slice)
    float* __restrict__ cOut2)            // nullptr or stride THn
{
    __shared__ float As[16][36];   // [batch][k] pad->36 (144B, 16B-aligned rows)
    __shared__ float Bs[32][68];   // [k][n] pad->68 (272B, 16B-aligned rows)

    const int tid = threadIdx.x;
    const int bx = blockIdx.x;     // N tile
    const int by = blockIdx.y;     // M tile
    const int jj = tid & 15;       // hidden unit within tile
    const int bb = tid >> 4;       // batch row within tile (0..15)

    float acc[4] = {0.f, 0.f, 0.f, 0.f};

    const int lrow = tid >> 3;         // A loader: 0..31 -> only tid<128 valid (16 rows)
    const int lk4  = (tid & 7) * 4;
    const int brow = tid >> 4;         // B loader rows brow, brow+16
    const int bcol4 = (tid & 15) * 4;

    for (int kt = 0; kt < Kc; kt += 32) {
        if (tid < 128) {
            int row = by * 16 + lrow;
            int k0 = kt + lk4;
            const float* src; long stride; int kk;
            if (k0 < 512) { src = x; stride = xStride; kk = k0; }
            else          { src = h; stride = hStride; kk = k0 - 512; }
            float4 v = *(const float4*)(src + (long)row * stride + kk);
            *(float4*)&As[lrow][lk4] = v;
        }
        {
            const float* wp = W + (long)(kt + brow) * Nc + bx * 64 + bcol4;
            float4 v0 = *(const float4*)(wp);
            float4 v1 = *(const float4*)(wp + 16L * Nc);
            *(float4*)&Bs[brow][bcol4] = v0;
            *(float4*)&Bs[brow + 16][bcol4] = v1;
        }
        __syncthreads();
        #pragma unroll
        for (int kq = 0; kq < 32; kq += 4) {
            float4 a = *(const float4*)&As[bb][kq];
            const float* ap = (const float*)&a;
            #pragma unroll
            for (int q = 0; q < 4; ++q) {
                float4 bv = *(const float4*)&Bs[kq + q][jj * 4];
                float av = ap[q];
                acc[0] += av * bv.x;
                acc[1] += av * bv.y;
                acc[2] += av * bv.z;
                acc[3] += av * bv.w;
            }
        }
        __syncthreads();
    }

    // epilogue: this thread has i,f,g,o for (row, jglob)
    const int row = by * 16 + bb;
    const int n40 = bx * 64 + jj * 4;
    const int jglob = n40 >> 2;
    float iv = acc[0] + bsum[n40 + 0];
    float fv = acc[1] + bsum[n40 + 1];
    float gv = acc[2] + bsum[n40 + 2];
    float ov = acc[3] + bsum[n40 + 3];
    float cold = c ? c[row * Hn + jglob] : 0.f;
    float si = 1.f / (1.f + expf(-iv));
    float sf = 1.f / (1.f + expf(-fv));
    float so = 1.f / (1.f + expf(-ov));
    float cn = sf * cold + si * tanhf(gv);
    float hn = so * tanhf(cn);
    hOut[row * Hn + jglob] = hn;
    cOut[row * Hn + jglob] = cn;
    if (hOut2) {
        hOut2[(long)row * THn + jglob] = hn;
        cOut2[(long)row * THn + jglob] = cn;
    }
}

// ---- Final state copy: ws [l][b][h] -> d_out [b][l][h] ----
__global__ __launch_bounds__(256) void final_copy(const float* __restrict__ H1f,
                                                  const float* __restrict__ M1f,
                                                  float* __restrict__ outH1,
                                                  float* __restrict__ outM1) {
    int idx = blockIdx.x * 256 + threadIdx.x;   // < 2*128*512
    int hh = idx & 511;
    int bl = idx >> 9;          // l*128 + b
    int l = bl >> 7;
    int b = bl & 127;
    long o = ((long)b * 2 + l) * 512 + hh;
    outH1[o] = H1f[idx];
    outM1[o] = M1f[idx];
}

extern "C" void kernel_launch(void* const* d_in, const int* in_sizes, int n_in,
                              void* d_out, int out_size, void* d_ws, size_t ws_size,
                              hipStream_t stream) {
    const float* H0in = (const float*)d_in[0];
    const float* Wih  = (const float*)d_in[1];
    const float* Whh  = (const float*)d_in[2];
    const float* bih  = (const float*)d_in[3];
    const float* bhh  = (const float*)d_in[4];
    float* out = (float*)d_out;
    float* ws  = (float*)d_ws;

    float* Wcat = ws + WCAT_OFF;
    float* bsum = ws + BSUM_OFF;
    float* h0A  = ws + H0A_OFF;
    float* h0B  = ws + H0B_OFF;
    float* H1b  = ws + H1_OFF;    // [2][2][B][H]
    float* M1   = ws + M1_OFF;    // [2][B][H]
    float* m0   = ws + M0_OFF;

    transform_w<<<(4 * Kc * Nc) / 256, 256, 0, stream>>>(Wih, Whh, Wcat);
    transform_b<<<(4 * Nc) / 256, 256, 0, stream>>>(bih, bhh, bsum);
    hipMemsetAsync(H1b, 0, 4L * Bn * Hn * sizeof(float), stream);  // both parities
    hipMemsetAsync(M1, 0, 2L * Bn * Hn * sizeof(float), stream);

    float* outH0 = out;                          // [B][T][H]
    float* outH1 = out + (long)Bn * Tn * Hn;     // [B][L][H]
    float* outM0 = outH1 + 2L * Bn * Hn;         // [B][T][H]
    float* outM1 = outM0 + (long)Bn * Tn * Hn;   // [B][L][H]

    dim3 grid(Nc / 64, Bn / 16);   // 32 x 8 = 256 blocks
    const long LBH = (long)Bn * Hn;

    for (int t = 0; t < Tn; ++t) {
        int p = t & 1;
        float* H1r = H1b + (long)p * 2 * LBH;
        float* H1w = H1b + (long)(1 - p) * 2 * LBH;
        // c00: x=H1_old[0], h=H0[:,t], c=0 -> h0A, m0
        lstm_cell<<<grid, 256, 0, stream>>>(H1r, (long)Hn, H0in + (long)t * Hn, THn, nullptr,
            Wcat + 0L * Kc * Nc, bsum + 0 * Nc, h0A, m0, nullptr, nullptr);
        // c01: x=h0A, h=H1_old[0], c=M1[0] -> H1_new[0], M1[0]
        lstm_cell<<<grid, 256, 0, stream>>>(h0A, (long)Hn, H1r, (long)Hn, M1,
            Wcat + 1L * Kc * Nc, bsum + 1 * Nc, H1w, M1, nullptr, nullptr);
        // c10: x=H1_old[1], h=h0A, c=m0 -> h0B, m0 (+ H0_out[:,t], M0_out[:,t])
        lstm_cell<<<grid, 256, 0, stream>>>(H1r + LBH, (long)Hn, h0A, (long)Hn, m0,
            Wcat + 2L * Kc * Nc, bsum + 2 * Nc, h0B, m0,
            outH0 + (long)t * Hn, outM0 + (long)t * Hn);
        // c11: x=h0B, h=H1_old[1], c=M1[1] -> H1_new[1], M1[1]
        lstm_cell<<<grid, 256, 0, stream>>>(h0B, (long)Hn, H1r + LBH, (long)Hn, M1 + LBH,
            Wcat + 3L * Kc * Nc, bsum + 3 * Nc, H1w + LBH, M1 + LBH, nullptr, nullptr);
    }

    // T=256 even: last write parity -> buffer 0
    final_copy<<<(2 * Bn * Hn) / 256, 256, 0, stream>>>(H1b, M1, outH1, outM1);
}

// Round 2
// 10016.158 us; speedup vs baseline: 4.1321x; 4.1321x over previous
//
#include <hip/hip_runtime.h>
#include <math.h>

// Grid-LSTM B=128, T=256, L=2, H=512 fp32 in/out, bf16 MFMA compute.
// Pipeline: A(t)={c00(t), c11(t-1)}, B(t)={c01(t), c10(t)} -> 512 two-cell launches.

static constexpr int Hn = 512;
static constexpr int Bn = 128;
static constexpr int Tn = 256;
static constexpr long THn = (long)Tn * Hn;     // 131072
static constexpr long LBH = (long)Bn * Hn;     // 65536
static constexpr long WT_ELEMS = 4L * 2048 * 1024;  // 8388608 bf16 per all cells
static constexpr long WCELL = 2048L * 1024;

typedef __attribute__((ext_vector_type(8))) short short8;
typedef __attribute__((ext_vector_type(4))) float floatx4;

__device__ __forceinline__ unsigned short f2bf(float f) {
    unsigned u = __builtin_bit_cast(unsigned, f);
    unsigned r = u + 0x7FFFu + ((u >> 16) & 1u);   // RNE
    return (unsigned short)(r >> 16);
}
__device__ __forceinline__ unsigned pk2(float a, float b) {
    return (unsigned)f2bf(a) | ((unsigned)f2bf(b) << 16);
}

// ---- Weight transform: Wt[cell][g][j][k] bf16, k contiguous (1024) ----
__global__ __launch_bounds__(256) void transform_w(const float* __restrict__ Wih,
                                                   const float* __restrict__ Whh,
                                                   unsigned short* __restrict__ Wt) {
    long idx = (long)blockIdx.x * 256 + threadIdx.x;   // < 8388608
    int k = (int)(idx & 1023);
    int j = (int)((idx >> 10) & 511);
    int g = (int)((idx >> 19) & 3);
    int cell = (int)(idx >> 21);
    int n = g * 512 + j;
    const float* src = (k < 512) ? Wih : Whh;
    float v = src[((long)cell * 2048 + n) * 512 + (k & 511)];
    Wt[idx] = f2bf(v);
}

// bias sum: identity layout [cell][g*512+j]
__global__ __launch_bounds__(256) void transform_b(const float* __restrict__ bih,
                                                   const float* __restrict__ bhh,
                                                   float* __restrict__ bsum) {
    int idx = blockIdx.x * 256 + threadIdx.x;   // < 8192
    bsum[idx] = bih[idx] + bhh[idx];
}

struct CellArgs {
    const float* x;            // [B][.] stride xs
    const float* h;            // [B][.] stride hs
    const float* c;            // [B][512] or nullptr (zeros)
    const unsigned short* W;   // bf16 [4g][512j][1024k]
    const float* b;            // fp32 [4g*512]
    float* hOut;               // [B][512]
    float* cOut;               // [B][512]
    float* hOut2;              // nullptr or stride THn
    float* cOut2;
    long xs, hs;
};

// ---- Fused bf16-MFMA LSTM cell ----
// Block: 32 rows x 32 j (x 4 gates = 128 cols), K=1024, BK=128, 256 thr = 4 waves.
// Wave (rw, jw): 16 rows x 16 j, 4 MFMA accs (one per gate) -> fused epilogue.
// Grid: (16 j-tiles, 4 row-tiles, ncells)
__global__ __launch_bounds__(256, 2) void lstm_cell_mfma(CellArgs a0, CellArgs a1) {
    const CellArgs a = (blockIdx.z == 0) ? a0 : a1;

    __shared__ unsigned short As[32 * 136];        // [row][k] pad 128->136
    __shared__ unsigned short Bs[4 * 32 * 136];    // [g*32+j][k] pad

    const int tid = threadIdx.x;
    const int lane = tid & 63;
    const int wid = tid >> 6;
    const int rw = wid >> 1, jw = wid & 1;
    const int q = lane >> 4, m16 = lane & 15;
    const int blockJ = blockIdx.x * 32;
    const int blockR = blockIdx.y * 32;

    floatx4 acc[4];
    #pragma unroll
    for (int g = 0; g < 4; ++g) acc[g] = (floatx4){0.f, 0.f, 0.f, 0.f};

    // staging assignments
    const int ar = tid >> 3, ac = (tid & 7) * 16;          // A: row 0..31, col16
    const int br = tid >> 1, bk = (tid & 1) * 64;          // B: (g,j) row 0..127
    const int bg = br >> 5, bj = br & 31;
    const unsigned short* Wrow = a.W + ((long)(bg * 512 + blockJ + bj)) * 1024 + bk;

    for (int k0 = 0; k0 < 1024; k0 += 128) {
        // --- stage A (fp32 -> bf16) ---
        {
            const float* src; long stride; int kk;
            if (k0 < 512) { src = a.x; stride = a.xs; kk = k0; }
            else          { src = a.h; stride = a.hs; kk = k0 - 512; }
            const float* p = src + (long)(blockR + ar) * stride + kk + ac;
            float4 v0 = *(const float4*)(p);
            float4 v1 = *(const float4*)(p + 4);
            float4 v2 = *(const float4*)(p + 8);
            float4 v3 = *(const float4*)(p + 12);
            uint4 w0 = {pk2(v0.x, v0.y), pk2(v0.z, v0.w), pk2(v1.x, v1.y), pk2(v1.z, v1.w)};
            uint4 w1 = {pk2(v2.x, v2.y), pk2(v2.z, v2.w), pk2(v3.x, v3.y), pk2(v3.z, v3.w)};
            *(uint4*)&As[ar * 136 + ac] = w0;
            *(uint4*)&As[ar * 136 + ac + 8] = w1;
        }
        // --- stage B (bf16 copy) ---
        {
            const unsigned short* wp = Wrow + k0;
            #pragma unroll
            for (int i = 0; i < 8; ++i) {
                uint4 d = *(const uint4*)(wp + i * 8);
                *(uint4*)&Bs[br * 136 + bk + i * 8] = d;
            }
        }
        __syncthreads();
        #pragma unroll
        for (int ks = 0; ks < 4; ++ks) {
            short8 af = *(const short8*)&As[(rw * 16 + m16) * 136 + ks * 32 + q * 8];
            #pragma unroll
            for (int g = 0; g < 4; ++g) {
                short8 bf = *(const short8*)&Bs[(g * 32 + jw * 16 + m16) * 136 + ks * 32 + q * 8];
                acc[g] = __builtin_amdgcn_mfma_f32_16x16x32_bf16(af, bf, acc[g], 0, 0, 0);
            }
        }
        __syncthreads();
    }

    // --- fused epilogue: lane has i,f,g,o for rows q*4+reg, col j ---
    const int jglob = blockJ + jw * 16 + m16;
    const float bi = a.b[jglob];
    const float bff = a.b[512 + jglob];
    const float bgg = a.b[1024 + jglob];
    const float bo = a.b[1536 + jglob];
    #pragma unroll
    for (int reg = 0; reg < 4; ++reg) {
        int row = blockR + rw * 16 + q * 4 + reg;
        float iv = acc[0][reg] + bi;
        float fv = acc[1][reg] + bff;
        float gv = acc[2][reg] + bgg;
        float ov = acc[3][reg] + bo;
        float cold = a.c ? a.c[row * Hn + jglob] : 0.f;
        float si = 1.f / (1.f + expf(-iv));
        float sf = 1.f / (1.f + expf(-fv));
        float so = 1.f / (1.f + expf(-ov));
        float cn = sf * cold + si * tanhf(gv);
        float hn = so * tanhf(cn);
        a.hOut[row * Hn + jglob] = hn;
        a.cOut[row * Hn + jglob] = cn;
        if (a.hOut2) {
            a.hOut2[(long)row * THn + jglob] = hn;
            a.cOut2[(long)row * THn + jglob] = cn;
        }
    }
}

// ---- Final state copy: ws [l][b][h] -> d_out [b][l][h] ----
__global__ __launch_bounds__(256) void final_copy(const float* __restrict__ H1f,
                                                  const float* __restrict__ M1f,
                                                  float* __restrict__ outH1,
                                                  float* __restrict__ outM1) {
    int idx = blockIdx.x * 256 + threadIdx.x;   // < 2*128*512
    int hh = idx & 511;
    int bl = idx >> 9;
    int l = bl >> 7;
    int b = bl & 127;
    long o = ((long)b * 2 + l) * 512 + hh;
    outH1[o] = H1f[idx];
    outM1[o] = M1f[idx];
}

extern "C" void kernel_launch(void* const* d_in, const int* in_sizes, int n_in,
                              void* d_out, int out_size, void* d_ws, size_t ws_size,
                              hipStream_t stream) {
    const float* H0in = (const float*)d_in[0];
    const float* Wih  = (const float*)d_in[1];
    const float* Whh  = (const float*)d_in[2];
    const float* bih  = (const float*)d_in[3];
    const float* bhh  = (const float*)d_in[4];
    float* out = (float*)d_out;

    unsigned short* Wt = (unsigned short*)d_ws;
    float* f = (float*)((char*)d_ws + WT_ELEMS * sizeof(unsigned short));  // 16 MB offset
    float* bsum = f;                 // 4*2048
    float* h0A  = bsum + 4L * 2048;  // [B][H]
    float* h0B  = h0A + LBH;
    float* H1b  = h0B + LBH;         // [2 parity][2 layer][B][H]
    float* M1   = H1b + 4L * LBH;    // [2 layer][B][H]
    float* m0   = M1 + 2L * LBH;     // [B][H]

    transform_w<<<(int)(WT_ELEMS / 256), 256, 0, stream>>>(Wih, Whh, Wt);
    transform_b<<<32, 256, 0, stream>>>(bih, bhh, bsum);
    hipMemsetAsync(H1b, 0, 6L * LBH * sizeof(float), stream);  // H1b + M1

    float* outH0 = out;
    float* outH1 = out + (long)Bn * THn;
    float* outM0 = outH1 + 2L * LBH;
    float* outM1 = outM0 + (long)Bn * THn;

    auto c00 = [&](int t) -> CellArgs {
        int p = t & 1;
        return {H1b + (long)p * 2 * LBH, H0in + (long)t * Hn, nullptr,
                Wt + 0 * WCELL, bsum + 0 * 2048, h0A, m0, nullptr, nullptr,
                (long)Hn, THn};
    };
    auto c01 = [&](int t) -> CellArgs {
        int p = t & 1;
        return {h0A, H1b + (long)p * 2 * LBH, M1,
                Wt + 1 * WCELL, bsum + 1 * 2048,
                H1b + (long)(1 - p) * 2 * LBH, M1, nullptr, nullptr,
                (long)Hn, (long)Hn};
    };
    auto c10 = [&](int t) -> CellArgs {
        int p = t & 1;
        return {H1b + (long)p * 2 * LBH + LBH, h0A, m0,
                Wt + 2 * WCELL, bsum + 2 * 2048, h0B, m0,
                outH0 + (long)t * Hn, outM0 + (long)t * Hn,
                (long)Hn, (long)Hn};
    };
    auto c11 = [&](int t) -> CellArgs {
        int p = t & 1;
        return {h0B, H1b + (long)p * 2 * LBH + LBH, M1 + LBH,
                Wt + 3 * WCELL, bsum + 3 * 2048,
                H1b + (long)(1 - p) * 2 * LBH + LBH, M1 + LBH, nullptr, nullptr,
                (long)Hn, (long)Hn};
    };

    dim3 blk(256);
    // stage A(0): c00(0) alone
    {
        CellArgs a = c00(0);
        lstm_cell_mfma<<<dim3(16, 4, 1), blk, 0, stream>>>(a, a);
    }
    for (int t = 0; t < Tn; ++t) {
        // stage B(t): c01(t) & c10(t)
        lstm_cell_mfma<<<dim3(16, 4, 2), blk, 0, stream>>>(c01(t), c10(t));
        if (t < Tn - 1) {
            // stage A(t+1): c00(t+1) & c11(t)
            lstm_cell_mfma<<<dim3(16, 4, 2), blk, 0, stream>>>(c00(t + 1), c11(t));
        }
    }
    {
        CellArgs a = c11(Tn - 1);
        lstm_cell_mfma<<<dim3(16, 4, 1), blk, 0, stream>>>(a, a);
    }
    final_copy<<<(int)(2 * LBH / 256), 256, 0, stream>>>(H1b, M1, outH1, outM1);
}